// Round 7
// baseline (552.429 us; speedup 1.0000x reference)
//
#include <hip/hip_runtime.h>
#include <hip/hip_bf16.h>
#include <cstdint>

#define B_ 8
#define T_ 4096
#define D_ 768
#define H_ 12
#define M_ (B_*T_)          // 32768 rows
#define CHUNKS 256
#define CLEN 16             // CHUNKS*CLEN == T_
#define WELEM (D_*D_)       // 589824
#define NCH (B_*H_*64)      // 6144 scan channels

typedef __attribute__((ext_vector_type(8))) short bf16x8;
typedef __attribute__((ext_vector_type(4))) float f32x4;

static __device__ __forceinline__ unsigned short f2bf(float f) {
  __hip_bfloat16 h = __float2bfloat16(f);
  return __builtin_bit_cast(unsigned short, h);
}
static __device__ __forceinline__ float bf2f(unsigned short u) {
  unsigned v = ((unsigned)u) << 16;
  return __builtin_bit_cast(float, v);
}

static __device__ __forceinline__ void async16(const void* g, void* l) {
  __builtin_amdgcn_global_load_lds(
      (const __attribute__((address_space(1))) unsigned int*)g,
      (__attribute__((address_space(3))) unsigned int*)l, 16, 0, 0);
}

// ---------------- fallback: zero the output (ws too small diagnostic) ----------------
__global__ __launch_bounds__(256) void zero_out_kernel(float* __restrict__ out, size_t n4) {
  size_t gid = (size_t)blockIdx.x * 256 + threadIdx.x;
  if (gid < n4) *(float4*)(out + gid * 4) = make_float4(0.f, 0.f, 0.f, 0.f);
}

// ---------------- token-shift mix: xr/xk/xv (bf16) ----------------
__global__ __launch_bounds__(256) void mix_kernel(
    const float* __restrict__ x, const float* __restrict__ tmr,
    const float* __restrict__ tmk, const float* __restrict__ tmv,
    unsigned short* __restrict__ xr, unsigned short* __restrict__ xk,
    unsigned short* __restrict__ xv) {
  size_t gid = (size_t)blockIdx.x * 256 + threadIdx.x;
  size_t idx4 = gid * 4;
  int d = (int)(idx4 % D_);
  size_t row = idx4 / D_;
  int t = (int)(row & (T_ - 1));
  float4 xc = *(const float4*)(x + idx4);
  float4 xp = make_float4(0.f, 0.f, 0.f, 0.f);
  if (t > 0) xp = *(const float4*)(x + idx4 - D_);
  float4 mr = *(const float4*)(tmr + d);
  float4 mk = *(const float4*)(tmk + d);
  float4 mv = *(const float4*)(tmv + d);
  ushort4 orr, okk, ovv;
  orr.x = f2bf(xc.x*mr.x + xp.x*(1.f-mr.x));
  orr.y = f2bf(xc.y*mr.y + xp.y*(1.f-mr.y));
  orr.z = f2bf(xc.z*mr.z + xp.z*(1.f-mr.z));
  orr.w = f2bf(xc.w*mr.w + xp.w*(1.f-mr.w));
  okk.x = f2bf(xc.x*mk.x + xp.x*(1.f-mk.x));
  okk.y = f2bf(xc.y*mk.y + xp.y*(1.f-mk.y));
  okk.z = f2bf(xc.z*mk.z + xp.z*(1.f-mk.z));
  okk.w = f2bf(xc.w*mk.w + xp.w*(1.f-mk.w));
  ovv.x = f2bf(xc.x*mv.x + xp.x*(1.f-mv.x));
  ovv.y = f2bf(xc.y*mv.y + xp.y*(1.f-mv.y));
  ovv.z = f2bf(xc.z*mv.z + xp.z*(1.f-mv.z));
  ovv.w = f2bf(xc.w*mv.w + xp.w*(1.f-mv.w));
  *(ushort4*)(xr + idx4) = orr;
  *(ushort4*)(xk + idx4) = okk;
  *(ushort4*)(xv + idx4) = ovv;
}

// ---------------- weight fp32 -> bf16 (3 matrices: Wr, Wk, Wv) ----------------
__global__ __launch_bounds__(256) void wconv_kernel(
    const float* __restrict__ a, const float* __restrict__ b,
    const float* __restrict__ c, unsigned short* __restrict__ o) {
  size_t gid = (size_t)blockIdx.x * 256 + threadIdx.x;
  size_t idx4 = gid * 4;
  size_t mi = idx4 / WELEM;
  size_t off = idx4 % WELEM;
  const float* src = (mi == 0) ? a : (mi == 1) ? b : c;
  float4 v = *(const float4*)(src + off);
  ushort4 u;
  u.x = f2bf(v.x); u.y = f2bf(v.y); u.z = f2bf(v.z); u.w = f2bf(v.w);
  *(ushort4*)(o + idx4) = u;
}

// ---- GEMM: C[M,768] = A[M,768] @ Bw[768,768]^T. ACT: 1=sigmoid. OBF: 1=bf16 out.
// BIAS: B selected per batch (Wo_b[b]) + bias2[b][n] added (GN folded into GEMM).
// BM=256 x BN=128, 4 waves, WAVE TILE 128x64 (AI=42.7 vs 32 — cuts LDS read/MFMA).
// BK=32, 2-stage dbuf (48 KB LDS), stage-next-early + syncthreads, XOR-swizzled LDS,
// XCD-chunked block swizzle, LDS-staged bf16 epilogue (two 128-row passes).
template<int ACT, int OBF, int BIAS>
__global__ __launch_bounds__(256, 2) void gemm_nt(
    const unsigned short* __restrict__ A,
    const unsigned short* __restrict__ Bw,
    void* __restrict__ Cv, const float* __restrict__ bias2) {
  __shared__ __align__(16) unsigned short smem[2][12288];   // 2 x 24 KB = 48 KB
  const int tid = threadIdx.x;
  const int wave = tid >> 6, lane = tid & 63;
  const int quad = lane >> 4, l16 = lane & 15;

  // XCD-aware chunked swizzle (bijective even when nwg % 8 != 0)
  int nwg = gridDim.x * gridDim.y;
  int lin = blockIdx.y * gridDim.x + blockIdx.x;
  int q = nwg >> 3, r = nwg & 7;
  int xcd = lin & 7, off = lin >> 3;
  int swz = (xcd < r ? xcd * (q + 1) : r * (q + 1) + (xcd - r) * q) + off;
  const int m0 = (swz / gridDim.x) * 256;
  const int n0 = (swz % gridDim.x) * 128;
  const int wr = wave >> 1, wc = wave & 1;   // 2M x 2N waves
  const int bb = m0 >> 12;                   // batch index (blocks never straddle)
  const unsigned short* Bp = BIAS ? Bw + (size_t)bb * WELEM : Bw;

  // stage one BK=32 tile: A 256x32 (16 KB, granules 0..1023) + B 128x32 (8 KB).
  auto stage = [&](int buf, int kb) {
    unsigned short* As = smem[buf];
    unsigned short* Bs = smem[buf] + 8192;
#pragma unroll
    for (int j = 0; j < 4; ++j) {
      int chunk = j * 256 + tid;             // 0..1023
      int row = chunk >> 2, slot = chunk & 3;
      int ks = slot ^ ((row >> 1) & 3);      // pre-swizzled global source granule
      async16(A + ((size_t)(m0 + row)) * D_ + kb + ks * 8, &As[chunk * 8]);
    }
#pragma unroll
    for (int j = 0; j < 2; ++j) {
      int chunk = j * 256 + tid;             // 0..511
      int row = chunk >> 2, slot = chunk & 3;
      int ks = slot ^ ((row >> 1) & 3);
      async16(Bp + ((size_t)(n0 + row)) * D_ + kb + ks * 8, &Bs[chunk * 8]);
    }
  };

  f32x4 acc[8][4] = {};
  const int NT = D_ / 32;                    // 24 K-tiles

  stage(0, 0);
  __syncthreads();                           // buf0 ready
  int cur = 0;
  for (int t = 0; t < NT; ++t) {
    if (t + 1 < NT) stage(cur ^ 1, (t + 1) * 32);   // issue next tile EARLY
    const unsigned short* As = smem[cur];
    const unsigned short* Bs = smem[cur] + 8192;
    bf16x8 a[8], b[4];
#pragma unroll
    for (int i = 0; i < 8; ++i) {
      int ra = wr * 128 + i * 16 + l16;
      a[i] = *(const bf16x8*)&As[ra * 32 + ((quad ^ ((ra >> 1) & 3)) * 8)];
    }
#pragma unroll
    for (int j = 0; j < 4; ++j) {
      int rb = wc * 64 + j * 16 + l16;
      b[j] = *(const bf16x8*)&Bs[rb * 32 + ((quad ^ ((rb >> 1) & 3)) * 8)];
    }
#pragma unroll
    for (int i = 0; i < 8; ++i)
#pragma unroll
      for (int jj = 0; jj < 4; ++jj)
        acc[i][jj] = __builtin_amdgcn_mfma_f32_16x16x32_bf16(a[i], b[jj], acc[i][jj], 0, 0, 0);
    __syncthreads();                         // next buf ready; cur reads done
    cur ^= 1;
  }

  if (OBF) {
    // LDS-staged epilogue in two 128-row passes (Cs = 128x128 bf16 = 32 KB,
    // contiguous within the 48 KB smem allocation).
    unsigned short* Cs = smem[0];
#pragma unroll
    for (int p = 0; p < 2; ++p) {
      if (wr == p) {
#pragma unroll
        for (int i = 0; i < 8; ++i) {
#pragma unroll
          for (int jj = 0; jj < 4; ++jj) {
            int col = wc * 64 + jj * 16 + l16;
#pragma unroll
            for (int rr = 0; rr < 4; ++rr) {
              int row = i * 16 + quad * 4 + rr;     // local 0..127
              float v = acc[i][jj][rr];
              if (ACT == 1) v = 1.f / (1.f + __expf(-v));
              int cg = (col >> 3) ^ (row & 7);
              Cs[row * 128 + cg * 8 + (col & 7)] = f2bf(v);
            }
          }
        }
      }
      __syncthreads();
#pragma unroll
      for (int g = 0; g < 8; ++g) {
        int gi = g * 256 + tid;              // 0..2047: 128 rows x 16 granules
        int row = gi >> 4, cg = gi & 15;
        int sg = cg ^ (row & 7);
        bf16x8 vv = *(const bf16x8*)&Cs[row * 128 + sg * 8];
        *(bf16x8*)((unsigned short*)Cv + (size_t)(m0 + p * 128 + row) * D_ + n0 + cg * 8) = vv;
      }
      __syncthreads();
    }
  } else {
    // fp32 out (+ per-batch GN bias when BIAS): quad-row 64B segments = full lines
#pragma unroll
    for (int i = 0; i < 8; ++i) {
      int rowb = m0 + wr * 128 + i * 16 + quad * 4;
#pragma unroll
      for (int jj = 0; jj < 4; ++jj) {
        int col = n0 + wc * 64 + jj * 16 + l16;
        float bias = BIAS ? bias2[bb * D_ + col] : 0.f;
#pragma unroll
        for (int rr = 0; rr < 4; ++rr) {
          float v = acc[i][jj][rr] + bias;
          ((float*)Cv)[(size_t)(rowb + rr) * D_ + col] = v;
        }
      }
    }
  }
}

// ---------------- WKV pass 1: per-chunk local scan, 8 channels/thread ----------------
__global__ __launch_bounds__(256) void wkv_pass1(
    const unsigned short* __restrict__ Kb, const unsigned short* __restrict__ Vb,
    const float* __restrict__ td,
    float* __restrict__ sumN, float* __restrict__ sumD) {
  int gid = blockIdx.x * 256 + threadIdx.x;   // ((c*B + b)*H + h)*8 + kg
  int kg = gid & 7;
  int tmp = gid >> 3;
  int h = tmp % H_;
  tmp /= H_;
  int b = tmp % B_;
  int c = tmp / B_;
  const float* tdp = td + h * 64 + kg * 8;
  float w[8], num[8], den[8];
#pragma unroll
  for (int j = 0; j < 8; ++j) {
    w[j] = __expf(-__expf(tdp[j]));
    num[j] = 0.f; den[j] = 0.f;
  }
  size_t base = ((size_t)(b * T_ + c * CLEN)) * D_ + h * 64 + kg * 8;
#pragma unroll 4
  for (int i = 0; i < CLEN; ++i) {
    bf16x8 k8 = *(const bf16x8*)(Kb + base + (size_t)i * D_);
    bf16x8 v8 = *(const bf16x8*)(Vb + base + (size_t)i * D_);
#pragma unroll
    for (int j = 0; j < 8; ++j) {
      float ek = __expf(bf2f((unsigned short)k8[j]));
      num[j] = num[j] * w[j] + ek * bf2f((unsigned short)v8[j]);
      den[j] = den[j] * w[j] + ek;
    }
  }
  int ob = ((c * B_ + b) * H_ + h) * 64 + kg * 8;
  *(float4*)(sumN + ob)     = make_float4(num[0], num[1], num[2], num[3]);
  *(float4*)(sumN + ob + 4) = make_float4(num[4], num[5], num[6], num[7]);
  *(float4*)(sumD + ob)     = make_float4(den[0], den[1], den[2], den[3]);
  *(float4*)(sumD + ob + 4) = make_float4(den[4], den[5], den[6], den[7]);
}

// ------- WKV pass 2: inter-chunk exclusive prefix — coalesced LDS-transposed scan -------
__global__ __launch_bounds__(256) void wkv_pass2(
    const float* __restrict__ sumN, const float* __restrict__ sumD,
    const float* __restrict__ td,
    float* __restrict__ prefN, float* __restrict__ prefD,
    float* __restrict__ gstats) {
  __shared__ float tile[256][64];           // 64KB
  int bid = blockIdx.x;                     // [0,192)
  if (bid == 0 && threadIdx.x < 192) gstats[threadIdx.x] = 0.f;
  int bh = bid >> 1, qd = bid & 1;
  const float* src = qd ? sumD : sumN;
  float* dst = qd ? prefD : prefN;
  int h = bh % H_;
  int base = bh * 64;                       // channel base within NCH
  int t = threadIdx.x;
  { // load: 16 rows x float4 per thread, coalesced
    int c4 = (t & 15) * 4;
    int rg = t >> 4;
#pragma unroll 4
    for (int i = 0; i < 16; ++i) {
      int row = rg * 16 + i;
      *(float4*)&tile[row][c4] = *(const float4*)&src[(size_t)row * NCH + base + c4];
    }
  }
  __syncthreads();
  int ch = t & 63, g = t >> 6;              // 4 groups x 64 rows
  float w = __expf(-__expf(td[h * 64 + ch]));
  float wL = w;
#pragma unroll
  for (int i = 0; i < 4; ++i) wL *= wL;     // w^16 (= w^CLEN)
  // serial inclusive scan within group, in place
  float v = 0.f;
  for (int i = 0; i < 64; ++i) {
    int row = g * 64 + i;
    v = v * wL + tile[row][ch];
    tile[row][ch] = v;
  }
  __syncthreads();
  // cross-group carry E_g
  float wL64 = wL;
#pragma unroll
  for (int i = 0; i < 6; ++i) wL64 *= wL64; // wL^64
  float E = 0.f;
  for (int gp = 0; gp < g; ++gp)            // g is wave-uniform
    E = E * wL64 + tile[gp * 64 + 63][ch];
  float f = 1.f;
  for (int i = 0; i < 64; ++i) {
    int row = g * 64 + i;
    float P = (i == 0) ? E : tile[row - 1][ch] + E * f;
    dst[(size_t)row * NCH + base + ch] = P;
    f *= wL;
  }
}

// --- WKV pass 3: wkv + y=r*wkv (in-place over r, bf16) + GN partial sums; 8 ch/thread ---
__global__ __launch_bounds__(256) void wkv_pass3(
    const unsigned short* __restrict__ Kb, const unsigned short* __restrict__ Vb,
    unsigned short* __restrict__ RY,
    const float* __restrict__ td, const float* __restrict__ tf,
    const float* __restrict__ prefN, const float* __restrict__ prefD,
    float* __restrict__ gsum, float* __restrict__ gsq) {
  int gid = blockIdx.x * 256 + threadIdx.x;   // ((c*B + b)*H + h)*8 + kg
  int kg = gid & 7;
  int tmp = gid >> 3;
  int h = tmp % H_;
  tmp /= H_;
  int b = tmp % B_;
  int c = tmp / B_;
  const float* tdp = td + h * 64 + kg * 8;
  const float* tfp = tf + h * 64 + kg * 8;
  float w[8], eu[8], num[8], den[8];
  int sb = ((c * B_ + b) * H_ + h) * 64 + kg * 8;
  float4 n0 = *(const float4*)(prefN + sb), n1 = *(const float4*)(prefN + sb + 4);
  float4 d0 = *(const float4*)(prefD + sb), d1 = *(const float4*)(prefD + sb + 4);
  num[0]=n0.x; num[1]=n0.y; num[2]=n0.z; num[3]=n0.w;
  num[4]=n1.x; num[5]=n1.y; num[6]=n1.z; num[7]=n1.w;
  den[0]=d0.x; den[1]=d0.y; den[2]=d0.z; den[3]=d0.w;
  den[4]=d1.x; den[5]=d1.y; den[6]=d1.z; den[7]=d1.w;
#pragma unroll
  for (int j = 0; j < 8; ++j) {
    w[j]  = __expf(-__expf(tdp[j]));
    eu[j] = __expf(tfp[j]);
  }
  size_t base = ((size_t)(b * T_ + c * CLEN)) * D_ + h * 64 + kg * 8;
  float s1 = 0.f, s2 = 0.f;
#pragma unroll 4
  for (int i = 0; i < CLEN; ++i) {
    size_t idx = base + (size_t)i * D_;
    bf16x8 k8 = *(const bf16x8*)(Kb + idx);
    bf16x8 v8 = *(const bf16x8*)(Vb + idx);
    bf16x8 r8 = *(const bf16x8*)(RY + idx);
    bf16x8 y8;
#pragma unroll
    for (int j = 0; j < 8; ++j) {
      float kk = bf2f((unsigned short)k8[j]);
      float vv = bf2f((unsigned short)v8[j]);
      float rr = bf2f((unsigned short)r8[j]);
      float ek = __expf(kk);
      float wkv = __fdividef(num[j] + eu[j] * ek * vv, den[j] + eu[j] * ek + 1e-9f);
      unsigned short ybf = f2bf(rr * wkv);
      y8[j] = (short)ybf;
      float y = bf2f(ybf);                 // stats on the stored (rounded) value
      s1 += y; s2 += y * y;
      num[j] = num[j] * w[j] + ek * vv;
      den[j] = den[j] * w[j] + ek;
    }
    *(bf16x8*)(RY + idx) = y8;
  }
#pragma unroll
  for (int off = 4; off; off >>= 1) {
    s1 += __shfl_xor(s1, off);
    s2 += __shfl_xor(s2, off);
  }
  if (kg == 0) {
    atomicAdd(&gsum[b * H_ + h], s1);
    atomicAdd(&gsq [b * H_ + h], s2);
  }
}

// ------- Wo scaling: Wo_b[b][n][d] = bf16(Wo[n][d] * rstd[b,h(d)] * gw[d]) -------
__global__ __launch_bounds__(256) void woprep_kernel(
    const float* __restrict__ Wo, const float* __restrict__ gsum,
    const float* __restrict__ gsq, const float* __restrict__ gw,
    unsigned short* __restrict__ Wob) {
  int blk = blockIdx.x;                    // 8 * 576
  int b = blk / (WELEM / 1024);
  size_t off = (size_t)(blk % (WELEM / 1024)) * 1024 + threadIdx.x * 4;
  int d = (int)(off % D_);                 // d..d+3 in same head (d%4==0)
  int g = b * H_ + (d >> 6);
  const float inv = 1.f / (float)(T_ * 64);
  float mean = gsum[g] * inv;
  float var = gsq[g] * inv - mean * mean;
  float rstd = rsqrtf(var + 1e-5f);
  float4 wo = *(const float4*)(Wo + off);
  float4 gwv = *(const float4*)(gw + d);
  ushort4 o;
  o.x = f2bf(wo.x * rstd * gwv.x);
  o.y = f2bf(wo.y * rstd * gwv.y);
  o.z = f2bf(wo.z * rstd * gwv.z);
  o.w = f2bf(wo.w * rstd * gwv.w);
  *(ushort4*)(Wob + (size_t)b * WELEM + off) = o;
}

// ------- bias2[b][n] = sum_d (gb[d] - mean*rstd*gw[d]) * Wo[n][d] -------
__global__ __launch_bounds__(256) void bias2_kernel(
    const float* __restrict__ Wo, const float* __restrict__ gsum,
    const float* __restrict__ gsq, const float* __restrict__ gw,
    const float* __restrict__ gb, float* __restrict__ bias2) {
  int blk = blockIdx.x;                    // 96 = 8 b x 12 nchunks
  int b = blk / 12, nb = (blk % 12) * 64;
  int lane = threadIdx.x & 63, wv = threadIdx.x >> 6;
  const float inv = 1.f / (float)(T_ * 64);
  float cB[12];
#pragma unroll
  for (int j = 0; j < 12; ++j) {
    int d = lane + 64 * j;                 // head(d) == j
    int g = b * H_ + j;
    float mean = gsum[g] * inv;
    float var = gsq[g] * inv - mean * mean;
    float rstd = rsqrtf(var + 1e-5f);
    cB[j] = gb[d] - mean * rstd * gw[d];
  }
  for (int n = nb + wv * 16, e = n + 16; n < e; ++n) {
    float s = 0.f;
#pragma unroll
    for (int j = 0; j < 12; ++j)
      s += cB[j] * Wo[(size_t)n * D_ + lane + 64 * j];
#pragma unroll
    for (int off = 32; off; off >>= 1) s += __shfl_down(s, off);
    if (lane == 0) bias2[b * D_ + n] = s;
  }
}

extern "C" void kernel_launch(void* const* d_in, const int* in_sizes, int n_in,
                              void* d_out, int out_size, void* d_ws, size_t ws_size,
                              hipStream_t stream) {
  (void)in_sizes; (void)n_in;
  const float* x   = (const float*)d_in[0];
  const float* tmr = (const float*)d_in[1];
  const float* tmk = (const float*)d_in[2];
  const float* tmv = (const float*)d_in[3];
  const float* td  = (const float*)d_in[4];
  const float* tf  = (const float*)d_in[5];
  const float* Wr  = (const float*)d_in[6];
  const float* Wk  = (const float*)d_in[7];
  const float* Wv  = (const float*)d_in[8];
  const float* Wo  = (const float*)d_in[9];
  const float* gw  = (const float*)d_in[10];
  const float* gb  = (const float*)d_in[11];
  float* out = (float*)d_out;

  constexpr size_t MD = (size_t)M_ * D_;
  constexpr size_t NEED = 4 * (MD * 2)              // XR, XK, XV, Rb (bf16)
                        + (size_t)4 * WELEM * 2     // Wb
                        + 4 * ((size_t)CHUNKS * NCH * 4)  // sumN/sumD/prefN/prefD
                        + 1024;                     // gstats
  if (ws_size < NEED) {
    zero_out_kernel<<<(int)((MD / 4 + 255) / 256), 256, 0, stream>>>(out, MD / 4);
    return;
  }

  char* ws = (char*)d_ws;
  unsigned short* XR = (unsigned short*)ws; ws += MD * 2;
  unsigned short* XK = (unsigned short*)ws; ws += MD * 2;
  unsigned short* XV = (unsigned short*)ws; ws += MD * 2;
  unsigned short* Rb = (unsigned short*)ws; ws += MD * 2;
  unsigned short* Wb = (unsigned short*)ws; ws += (size_t)4 * WELEM * 2;
  float* sumN  = (float*)ws; ws += (size_t)CHUNKS * NCH * 4;
  float* sumD  = (float*)ws; ws += (size_t)CHUNKS * NCH * 4;
  float* prefN = (float*)ws; ws += (size_t)CHUNKS * NCH * 4;
  float* prefD = (float*)ws; ws += (size_t)CHUNKS * NCH * 4;
  float* gstats = (float*)ws; ws += 1024;
  // aliases onto dead buffers (dataflow-checked):
  unsigned short* Kb = XR;                     // XR dead after gemm-r
  unsigned short* Vb = XK;                     // XK dead after gemm-k
  unsigned short* Wob = (unsigned short*)sumN; // sumN+sumD dead after pass2 (9.4MB <= 12.6MB)
  float* bias2 = prefN;                        // prefN dead after pass3

  mix_kernel<<<(int)(MD / 1024), 256, 0, stream>>>(x, tmr, tmk, tmv, XR, XK, XV);
  wconv_kernel<<<(3 * WELEM / 4) / 256, 256, 0, stream>>>(Wr, Wk, Wv, Wb);

  dim3 ggrid(D_ / 128, M_ / 256);              // 6 x 128 = 768 blocks
  gemm_nt<1, 1, 0><<<ggrid, 256, 0, stream>>>(XR, Wb,             Rb, nullptr);
  gemm_nt<0, 1, 0><<<ggrid, 256, 0, stream>>>(XK, Wb + WELEM,     Kb, nullptr);
  gemm_nt<0, 1, 0><<<ggrid, 256, 0, stream>>>(XV, Wb + 2 * WELEM, Vb, nullptr);

  wkv_pass1<<<(CHUNKS * NCH / 8) / 256, 256, 0, stream>>>(Kb, Vb, td, sumN, sumD);
  wkv_pass2<<<192, 256, 0, stream>>>(sumN, sumD, td, prefN, prefD, gstats);
  wkv_pass3<<<(CHUNKS * NCH / 8) / 256, 256, 0, stream>>>(Kb, Vb, Rb, td, tf,
                                                          prefN, prefD, gstats, gstats + 96);

  // GN folded into output GEMM: Wo_b = Wo * (rstd*gw) per batch; bias2 = cB @ Wo^T
  woprep_kernel<<<8 * (WELEM / 1024), 256, 0, stream>>>(Wo, gstats, gstats + 96, gw, Wob);
  bias2_kernel<<<96, 256, 0, stream>>>(Wo, gstats, gstats + 96, gw, gb, bias2);

  gemm_nt<0, 0, 1><<<ggrid, 256, 0, stream>>>(Rb, Wob, out, bias2);
}

// Round 8
// 500.227 us; speedup vs baseline: 1.1044x; 1.1044x over previous
//
#include <hip/hip_runtime.h>
#include <hip/hip_bf16.h>
#include <cstdint>

#define B_ 8
#define T_ 4096
#define D_ 768
#define H_ 12
#define M_ (B_*T_)          // 32768 rows
#define CHUNKS 256
#define CLEN 16             // CHUNKS*CLEN == T_
#define WELEM (D_*D_)       // 589824
#define NCH (B_*H_*64)      // 6144 scan channels

typedef __attribute__((ext_vector_type(8))) short bf16x8;
typedef __attribute__((ext_vector_type(4))) float f32x4;

static __device__ __forceinline__ unsigned short f2bf(float f) {
  __hip_bfloat16 h = __float2bfloat16(f);
  return __builtin_bit_cast(unsigned short, h);
}
static __device__ __forceinline__ float bf2f(unsigned short u) {
  unsigned v = ((unsigned)u) << 16;
  return __builtin_bit_cast(float, v);
}

static __device__ __forceinline__ void async16(const void* g, void* l) {
  __builtin_amdgcn_global_load_lds(
      (const __attribute__((address_space(1))) unsigned int*)g,
      (__attribute__((address_space(3))) unsigned int*)l, 16, 0, 0);
}

// ---------------- fallback: zero the output (ws too small diagnostic) ----------------
__global__ __launch_bounds__(256) void zero_out_kernel(float* __restrict__ out, size_t n4) {
  size_t gid = (size_t)blockIdx.x * 256 + threadIdx.x;
  if (gid < n4) *(float4*)(out + gid * 4) = make_float4(0.f, 0.f, 0.f, 0.f);
}

// ------- merged: token-shift mix (blocks 0..24575) + weight conv (blocks 24576..26303) -------
__global__ __launch_bounds__(256) void mixconv_kernel(
    const float* __restrict__ x, const float* __restrict__ tmr,
    const float* __restrict__ tmk, const float* __restrict__ tmv,
    const float* __restrict__ Wr, const float* __restrict__ Wk,
    const float* __restrict__ Wv,
    unsigned short* __restrict__ xr, unsigned short* __restrict__ xk,
    unsigned short* __restrict__ xv, unsigned short* __restrict__ wo) {
  int bid = blockIdx.x;
  if (bid < 24576) {
    size_t gid = (size_t)bid * 256 + threadIdx.x;
    size_t idx4 = gid * 4;
    int d = (int)(idx4 % D_);
    size_t row = idx4 / D_;
    int t = (int)(row & (T_ - 1));
    float4 xc = *(const float4*)(x + idx4);
    float4 xp = make_float4(0.f, 0.f, 0.f, 0.f);
    if (t > 0) xp = *(const float4*)(x + idx4 - D_);
    float4 mr = *(const float4*)(tmr + d);
    float4 mk = *(const float4*)(tmk + d);
    float4 mv = *(const float4*)(tmv + d);
    ushort4 orr, okk, ovv;
    orr.x = f2bf(xc.x*mr.x + xp.x*(1.f-mr.x));
    orr.y = f2bf(xc.y*mr.y + xp.y*(1.f-mr.y));
    orr.z = f2bf(xc.z*mr.z + xp.z*(1.f-mr.z));
    orr.w = f2bf(xc.w*mr.w + xp.w*(1.f-mr.w));
    okk.x = f2bf(xc.x*mk.x + xp.x*(1.f-mk.x));
    okk.y = f2bf(xc.y*mk.y + xp.y*(1.f-mk.y));
    okk.z = f2bf(xc.z*mk.z + xp.z*(1.f-mk.z));
    okk.w = f2bf(xc.w*mk.w + xp.w*(1.f-mk.w));
    ovv.x = f2bf(xc.x*mv.x + xp.x*(1.f-mv.x));
    ovv.y = f2bf(xc.y*mv.y + xp.y*(1.f-mv.y));
    ovv.z = f2bf(xc.z*mv.z + xp.z*(1.f-mv.z));
    ovv.w = f2bf(xc.w*mv.w + xp.w*(1.f-mv.w));
    *(ushort4*)(xr + idx4) = orr;
    *(ushort4*)(xk + idx4) = okk;
    *(ushort4*)(xv + idx4) = ovv;
  } else {
    size_t gid = (size_t)(bid - 24576) * 256 + threadIdx.x;
    size_t idx4 = gid * 4;
    size_t mi = idx4 / WELEM;
    size_t off = idx4 % WELEM;
    const float* src = (mi == 0) ? Wr : (mi == 1) ? Wk : Wv;
    float4 v = *(const float4*)(src + off);
    ushort4 u;
    u.x = f2bf(v.x); u.y = f2bf(v.y); u.z = f2bf(v.z); u.w = f2bf(v.w);
    *(ushort4*)(wo + idx4) = u;
  }
}

// ---- GEMM core (R4-proven): 128x128 tile, BK=32, 2-stage dbuf in 32 KB LDS,
// stage-next-early + syncthreads, XOR-swizzled LDS, LDS-staged bf16 epilogue. ----
template<int OBF, int BIAS>
static __device__ __forceinline__ void gemm_body(
    unsigned short* smem,
    const unsigned short* __restrict__ A,
    const unsigned short* __restrict__ Bp,   // batch-selected by caller
    void* __restrict__ Cv, const float* __restrict__ bias2,
    int m0, int n0, int bb, int act) {
  const int tid = threadIdx.x;
  const int wave = tid >> 6, lane = tid & 63;
  const int quad = lane >> 4, l16 = lane & 15;
  const int wm = (wave & 1) * 64, wn = (wave >> 1) * 64;

  auto stage = [&](int buf, int kb) {
    unsigned short* Ls = smem + buf * (128 * 64);
#pragma unroll
    for (int j = 0; j < 2; ++j) {
      int chunk = j * 256 + tid;           // 0..511 16B-granules
      int row = chunk >> 2, slot = chunk & 3;
      int ks = slot ^ ((row >> 1) & 3);    // pre-swizzled global source granule
      async16(A  + ((size_t)(m0 + row)) * D_ + kb + ks * 8, &Ls[chunk * 8]);
      async16(Bp + ((size_t)(n0 + row)) * D_ + kb + ks * 8, &Ls[128 * 32 + chunk * 8]);
    }
  };

  f32x4 acc[4][4] = {};
  const int NT = D_ / 32;                  // 24 K-tiles

  stage(0, 0);
  __syncthreads();                         // buf0 ready
  int cur = 0;
  for (int t = 0; t < NT; ++t) {
    if (t + 1 < NT) stage(cur ^ 1, (t + 1) * 32);   // issue next tile EARLY
    const unsigned short* As = smem + cur * (128 * 64);
    const unsigned short* Bs = As + 128 * 32;
    bf16x8 a[4], b[4];
#pragma unroll
    for (int i = 0; i < 4; ++i) {
      int ra = wm + i * 16 + l16;
      a[i] = *(const bf16x8*)&As[ra * 32 + ((quad ^ ((ra >> 1) & 3)) * 8)];
      int rb = wn + i * 16 + l16;
      b[i] = *(const bf16x8*)&Bs[rb * 32 + ((quad ^ ((rb >> 1) & 3)) * 8)];
    }
#pragma unroll
    for (int i = 0; i < 4; ++i)
#pragma unroll
      for (int jj = 0; jj < 4; ++jj)
        acc[i][jj] = __builtin_amdgcn_mfma_f32_16x16x32_bf16(a[i], b[jj], acc[i][jj], 0, 0, 0);
    __syncthreads();                       // next buf ready; cur reads done
    cur ^= 1;
  }

  if (OBF) {
    // LDS-staged epilogue: full 64B-line ushort8 stores
    unsigned short* Cs = smem;             // [128][128] bf16, granule-XOR swizzled
#pragma unroll
    for (int i = 0; i < 4; ++i) {
#pragma unroll
      for (int jj = 0; jj < 4; ++jj) {
        int col = wn + jj * 16 + l16;
#pragma unroll
        for (int rr = 0; rr < 4; ++rr) {
          int row = wm + i * 16 + quad * 4 + rr;
          float v = acc[i][jj][rr];
          if (act) v = 1.f / (1.f + __expf(-v));
          int cg = (col >> 3) ^ (row & 7);
          Cs[row * 128 + cg * 8 + (col & 7)] = f2bf(v);
        }
      }
    }
    __syncthreads();
#pragma unroll
    for (int g = 0; g < 8; ++g) {
      int gi = g * 256 + tid;              // 0..2047: 128 rows x 16 granules
      int row = gi >> 4, cg = gi & 15;
      int sg = cg ^ (row & 7);
      bf16x8 vv = *(const bf16x8*)&Cs[row * 128 + sg * 8];
      *(bf16x8*)((unsigned short*)Cv + (size_t)(m0 + row) * D_ + n0 + cg * 8) = vv;
    }
  } else {
    // fp32 out (+ per-batch GN bias when BIAS): quad-row 64B segments = full lines
#pragma unroll
    for (int i = 0; i < 4; ++i) {
      int rowb = m0 + wm + i * 16 + quad * 4;
#pragma unroll
      for (int jj = 0; jj < 4; ++jj) {
        int col = n0 + wn + jj * 16 + l16;
        float bias = BIAS ? bias2[bb * D_ + col] : 0.f;
#pragma unroll
        for (int rr = 0; rr < 4; ++rr) {
          float v = acc[i][jj][rr] + bias;
          ((float*)Cv)[(size_t)(rowb + rr) * D_ + col] = v;
        }
      }
    }
  }
}

// XCD-aware chunked swizzle (bijective even when nwg % 8 != 0)
static __device__ __forceinline__ void block_swz(int& m0, int& n0) {
  int nwg = gridDim.x * gridDim.y;
  int lin = blockIdx.y * gridDim.x + blockIdx.x;
  int q = nwg >> 3, r = nwg & 7;
  int xcd = lin & 7, off = lin >> 3;
  int swz = (xcd < r ? xcd * (q + 1) : r * (q + 1) + (xcd - r) * q) + off;
  m0 = (swz / gridDim.x) * 128;
  n0 = (swz % gridDim.x) * 128;
}

template<int ACT, int OBF, int BIAS>
__global__ __launch_bounds__(256, 3) void gemm_nt(
    const unsigned short* __restrict__ A,
    const unsigned short* __restrict__ Bw,
    void* __restrict__ Cv, const float* __restrict__ bias2) {
  __shared__ __align__(16) unsigned short smem[128 * 128];   // 32 KB
  int m0, n0;
  block_swz(m0, n0);
  const int bb = m0 >> 12;                 // batch index (blocks never straddle)
  const unsigned short* Bp = BIAS ? Bw + (size_t)bb * WELEM : Bw;
  gemm_body<OBF, BIAS>(smem, A, Bp, Cv, bias2, m0, n0, bb, ACT);
}

// merged QKV: z-slice selects {XR->Rb sigmoid, XK->Kb, XV->Vb} (requires un-aliased Kb/Vb)
__global__ __launch_bounds__(256, 3) void gemm_qkv(
    const unsigned short* __restrict__ XR, const unsigned short* __restrict__ XK,
    const unsigned short* __restrict__ XV, const unsigned short* __restrict__ Wb,
    unsigned short* __restrict__ Rb, unsigned short* __restrict__ Kb,
    unsigned short* __restrict__ Vb) {
  __shared__ __align__(16) unsigned short smem[128 * 128];   // 32 KB
  int m0, n0;
  block_swz(m0, n0);
  int z = blockIdx.z;
  const unsigned short* A = (z == 0) ? XR : (z == 1) ? XK : XV;
  unsigned short* C = (z == 0) ? Rb : (z == 1) ? Kb : Vb;
  gemm_body<1, 0>(smem, A, Wb + (size_t)z * WELEM, C, nullptr, m0, n0, 0, z == 0 ? 1 : 0);
}

// ---------------- WKV pass 1: per-chunk local scan, 8 channels/thread ----------------
__global__ __launch_bounds__(256) void wkv_pass1(
    const unsigned short* __restrict__ Kb, const unsigned short* __restrict__ Vb,
    const float* __restrict__ td,
    float* __restrict__ sumN, float* __restrict__ sumD) {
  int gid = blockIdx.x * 256 + threadIdx.x;   // ((c*B + b)*H + h)*8 + kg
  int kg = gid & 7;
  int tmp = gid >> 3;
  int h = tmp % H_;
  tmp /= H_;
  int b = tmp % B_;
  int c = tmp / B_;
  const float* tdp = td + h * 64 + kg * 8;
  float w[8], num[8], den[8];
#pragma unroll
  for (int j = 0; j < 8; ++j) {
    w[j] = __expf(-__expf(tdp[j]));
    num[j] = 0.f; den[j] = 0.f;
  }
  size_t base = ((size_t)(b * T_ + c * CLEN)) * D_ + h * 64 + kg * 8;
#pragma unroll 4
  for (int i = 0; i < CLEN; ++i) {
    bf16x8 k8 = *(const bf16x8*)(Kb + base + (size_t)i * D_);
    bf16x8 v8 = *(const bf16x8*)(Vb + base + (size_t)i * D_);
#pragma unroll
    for (int j = 0; j < 8; ++j) {
      float ek = __expf(bf2f((unsigned short)k8[j]));
      num[j] = num[j] * w[j] + ek * bf2f((unsigned short)v8[j]);
      den[j] = den[j] * w[j] + ek;
    }
  }
  int ob = ((c * B_ + b) * H_ + h) * 64 + kg * 8;
  *(float4*)(sumN + ob)     = make_float4(num[0], num[1], num[2], num[3]);
  *(float4*)(sumN + ob + 4) = make_float4(num[4], num[5], num[6], num[7]);
  *(float4*)(sumD + ob)     = make_float4(den[0], den[1], den[2], den[3]);
  *(float4*)(sumD + ob + 4) = make_float4(den[4], den[5], den[6], den[7]);
}

// ------- WKV pass 2: inter-chunk exclusive prefix — coalesced LDS-transposed scan -------
__global__ __launch_bounds__(256) void wkv_pass2(
    const float* __restrict__ sumN, const float* __restrict__ sumD,
    const float* __restrict__ td,
    float* __restrict__ prefN, float* __restrict__ prefD,
    float* __restrict__ gstats) {
  __shared__ float tile[256][64];           // 64KB
  int bid = blockIdx.x;                     // [0,192)
  if (bid == 0 && threadIdx.x < 192) gstats[threadIdx.x] = 0.f;
  int bh = bid >> 1, qd = bid & 1;
  const float* src = qd ? sumD : sumN;
  float* dst = qd ? prefD : prefN;
  int h = bh % H_;
  int base = bh * 64;                       // channel base within NCH
  int t = threadIdx.x;
  { // load: 16 rows x float4 per thread, coalesced
    int c4 = (t & 15) * 4;
    int rg = t >> 4;
#pragma unroll 4
    for (int i = 0; i < 16; ++i) {
      int row = rg * 16 + i;
      *(float4*)&tile[row][c4] = *(const float4*)&src[(size_t)row * NCH + base + c4];
    }
  }
  __syncthreads();
  int ch = t & 63, g = t >> 6;              // 4 groups x 64 rows
  float w = __expf(-__expf(td[h * 64 + ch]));
  float wL = w;
#pragma unroll
  for (int i = 0; i < 4; ++i) wL *= wL;     // w^16 (= w^CLEN)
  // serial inclusive scan within group, in place
  float v = 0.f;
  for (int i = 0; i < 64; ++i) {
    int row = g * 64 + i;
    v = v * wL + tile[row][ch];
    tile[row][ch] = v;
  }
  __syncthreads();
  // cross-group carry E_g
  float wL64 = wL;
#pragma unroll
  for (int i = 0; i < 6; ++i) wL64 *= wL64; // wL^64
  float E = 0.f;
  for (int gp = 0; gp < g; ++gp)            // g is wave-uniform
    E = E * wL64 + tile[gp * 64 + 63][ch];
  float f = 1.f;
  for (int i = 0; i < 64; ++i) {
    int row = g * 64 + i;
    float P = (i == 0) ? E : tile[row - 1][ch] + E * f;
    dst[(size_t)row * NCH + base + ch] = P;
    f *= wL;
  }
}

// --- WKV pass 3: wkv + y=r*wkv (in-place over r, bf16) + GN partial sums; 8 ch/thread ---
__global__ __launch_bounds__(256) void wkv_pass3(
    const unsigned short* __restrict__ Kb, const unsigned short* __restrict__ Vb,
    unsigned short* __restrict__ RY,
    const float* __restrict__ td, const float* __restrict__ tf,
    const float* __restrict__ prefN, const float* __restrict__ prefD,
    float* __restrict__ gsum, float* __restrict__ gsq) {
  int gid = blockIdx.x * 256 + threadIdx.x;   // ((c*B + b)*H + h)*8 + kg
  int kg = gid & 7;
  int tmp = gid >> 3;
  int h = tmp % H_;
  tmp /= H_;
  int b = tmp % B_;
  int c = tmp / B_;
  const float* tdp = td + h * 64 + kg * 8;
  const float* tfp = tf + h * 64 + kg * 8;
  float w[8], eu[8], num[8], den[8];
  int sb = ((c * B_ + b) * H_ + h) * 64 + kg * 8;
  float4 n0 = *(const float4*)(prefN + sb), n1 = *(const float4*)(prefN + sb + 4);
  float4 d0 = *(const float4*)(prefD + sb), d1 = *(const float4*)(prefD + sb + 4);
  num[0]=n0.x; num[1]=n0.y; num[2]=n0.z; num[3]=n0.w;
  num[4]=n1.x; num[5]=n1.y; num[6]=n1.z; num[7]=n1.w;
  den[0]=d0.x; den[1]=d0.y; den[2]=d0.z; den[3]=d0.w;
  den[4]=d1.x; den[5]=d1.y; den[6]=d1.z; den[7]=d1.w;
#pragma unroll
  for (int j = 0; j < 8; ++j) {
    w[j]  = __expf(-__expf(tdp[j]));
    eu[j] = __expf(tfp[j]);
  }
  size_t base = ((size_t)(b * T_ + c * CLEN)) * D_ + h * 64 + kg * 8;
  float s1 = 0.f, s2 = 0.f;
#pragma unroll 4
  for (int i = 0; i < CLEN; ++i) {
    size_t idx = base + (size_t)i * D_;
    bf16x8 k8 = *(const bf16x8*)(Kb + idx);
    bf16x8 v8 = *(const bf16x8*)(Vb + idx);
    bf16x8 r8 = *(const bf16x8*)(RY + idx);
    bf16x8 y8;
#pragma unroll
    for (int j = 0; j < 8; ++j) {
      float kk = bf2f((unsigned short)k8[j]);
      float vv = bf2f((unsigned short)v8[j]);
      float rr = bf2f((unsigned short)r8[j]);
      float ek = __expf(kk);
      float wkv = __fdividef(num[j] + eu[j] * ek * vv, den[j] + eu[j] * ek + 1e-9f);
      unsigned short ybf = f2bf(rr * wkv);
      y8[j] = (short)ybf;
      float y = bf2f(ybf);                 // stats on the stored (rounded) value
      s1 += y; s2 += y * y;
      num[j] = num[j] * w[j] + ek * vv;
      den[j] = den[j] * w[j] + ek;
    }
    *(bf16x8*)(RY + idx) = y8;
  }
#pragma unroll
  for (int off = 4; off; off >>= 1) {
    s1 += __shfl_xor(s1, off);
    s2 += __shfl_xor(s2, off);
  }
  if (kg == 0) {
    atomicAdd(&gsum[b * H_ + h], s1);
    atomicAdd(&gsq [b * H_ + h], s2);
  }
}

// ------- merged GN-fold prep: Wo scaling (blocks 0..4607) + bias2 (blocks 4608..4703) -------
// Wo_b[b][n][d] = bf16(Wo[n][d]*rstd[b,h(d)]*gw[d]); bias2[b][n] = sum_d cB[b,d]*Wo[n][d]
__global__ __launch_bounds__(256) void wofuse_kernel(
    const float* __restrict__ Wo, const float* __restrict__ gsum,
    const float* __restrict__ gsq, const float* __restrict__ gw,
    const float* __restrict__ gb, unsigned short* __restrict__ Wob,
    float* __restrict__ bias2) {
  const float inv = 1.f / (float)(T_ * 64);
  int bid = blockIdx.x;
  if (bid < 4608) {
    int b = bid / (WELEM / 1024);
    size_t off = (size_t)(bid % (WELEM / 1024)) * 1024 + threadIdx.x * 4;
    int d = (int)(off % D_);               // d..d+3 in same head (d%4==0)
    int g = b * H_ + (d >> 6);
    float mean = gsum[g] * inv;
    float var = gsq[g] * inv - mean * mean;
    float rstd = rsqrtf(var + 1e-5f);
    float4 wo = *(const float4*)(Wo + off);
    float4 gwv = *(const float4*)(gw + d);
    ushort4 o;
    o.x = f2bf(wo.x * rstd * gwv.x);
    o.y = f2bf(wo.y * rstd * gwv.y);
    o.z = f2bf(wo.z * rstd * gwv.z);
    o.w = f2bf(wo.w * rstd * gwv.w);
    *(ushort4*)(Wob + (size_t)b * WELEM + off) = o;
  } else {
    int blk = bid - 4608;                  // 96 = 8 b x 12 nchunks
    int b = blk / 12, nb = (blk % 12) * 64;
    int lane = threadIdx.x & 63, wv = threadIdx.x >> 6;
    float cB[12];
#pragma unroll
    for (int j = 0; j < 12; ++j) {
      int d = lane + 64 * j;               // head(d) == j
      int g = b * H_ + j;
      float mean = gsum[g] * inv;
      float var = gsq[g] * inv - mean * mean;
      float rstd = rsqrtf(var + 1e-5f);
      cB[j] = gb[d] - mean * rstd * gw[d];
    }
    for (int n = nb + wv * 16, e = n + 16; n < e; ++n) {
      float s = 0.f;
#pragma unroll
      for (int j = 0; j < 12; ++j)
        s += cB[j] * Wo[(size_t)n * D_ + lane + 64 * j];
#pragma unroll
      for (int off = 32; off; off >>= 1) s += __shfl_down(s, off);
      if (lane == 0) bias2[b * D_ + n] = s;
    }
  }
}

extern "C" void kernel_launch(void* const* d_in, const int* in_sizes, int n_in,
                              void* d_out, int out_size, void* d_ws, size_t ws_size,
                              hipStream_t stream) {
  (void)in_sizes; (void)n_in;
  const float* x   = (const float*)d_in[0];
  const float* tmr = (const float*)d_in[1];
  const float* tmk = (const float*)d_in[2];
  const float* tmv = (const float*)d_in[3];
  const float* td  = (const float*)d_in[4];
  const float* tf  = (const float*)d_in[5];
  const float* Wr  = (const float*)d_in[6];
  const float* Wk  = (const float*)d_in[7];
  const float* Wv  = (const float*)d_in[8];
  const float* Wo  = (const float*)d_in[9];
  const float* gw  = (const float*)d_in[10];
  const float* gb  = (const float*)d_in[11];
  float* out = (float*)d_out;

  constexpr size_t MD = (size_t)M_ * D_;
  constexpr size_t NEED_SMALL = 4 * (MD * 2)        // XR, XK, XV, Rb (bf16)
                        + (size_t)4 * WELEM * 2     // Wb
                        + 4 * ((size_t)CHUNKS * NCH * 4)  // sumN/sumD/prefN/prefD
                        + 1024;                     // gstats
  constexpr size_t NEED_BIG = NEED_SMALL + 2 * (MD * 2);  // + un-aliased Kb, Vb
  if (ws_size < NEED_SMALL) {
    zero_out_kernel<<<(int)((MD / 4 + 255) / 256), 256, 0, stream>>>(out, MD / 4);
    return;
  }
  const bool big = (ws_size >= NEED_BIG);

  char* ws = (char*)d_ws;
  unsigned short* XR = (unsigned short*)ws; ws += MD * 2;
  unsigned short* XK = (unsigned short*)ws; ws += MD * 2;
  unsigned short* XV = (unsigned short*)ws; ws += MD * 2;
  unsigned short* Rb = (unsigned short*)ws; ws += MD * 2;
  unsigned short* Wb = (unsigned short*)ws; ws += (size_t)4 * WELEM * 2;
  float* sumN  = (float*)ws; ws += (size_t)CHUNKS * NCH * 4;
  float* sumD  = (float*)ws; ws += (size_t)CHUNKS * NCH * 4;
  float* prefN = (float*)ws; ws += (size_t)CHUNKS * NCH * 4;
  float* prefD = (float*)ws; ws += (size_t)CHUNKS * NCH * 4;
  float* gstats = (float*)ws; ws += 1024;
  unsigned short* Kb2 = (unsigned short*)ws; ws += MD * 2;   // only used if big
  unsigned short* Vb2 = (unsigned short*)ws; ws += MD * 2;   // only used if big
  // small path aliases onto dead buffers (dataflow-checked):
  unsigned short* Kb = big ? Kb2 : XR;         // small: XR dead after gemm-r
  unsigned short* Vb = big ? Vb2 : XK;         // small: XK dead after gemm-k
  unsigned short* Wob = (unsigned short*)sumN; // sumN+sumD dead after pass2 (9.4MB <= 12.6MB)
  float* bias2 = prefN;                        // prefN dead after pass3

  mixconv_kernel<<<26304, 256, 0, stream>>>(x, tmr, tmk, tmv, Wr, Wk, Wv,
                                            XR, XK, XV, Wb);

  dim3 ggrid(D_ / 128, M_ / 128);              // 6 x 256 = 1536 blocks
  if (big) {
    dim3 qgrid(D_ / 128, M_ / 128, 3);         // 4608 blocks, one dispatch
    gemm_qkv<<<qgrid, 256, 0, stream>>>(XR, XK, XV, Wb, Rb, Kb2, Vb2);
  } else {
    gemm_nt<1, 1, 0><<<ggrid, 256, 0, stream>>>(XR, Wb,             Rb, nullptr);
    gemm_nt<0, 1, 0><<<ggrid, 256, 0, stream>>>(XK, Wb + WELEM,     Kb, nullptr);
    gemm_nt<0, 1, 0><<<ggrid, 256, 0, stream>>>(XV, Wb + 2 * WELEM, Vb, nullptr);
  }

  wkv_pass1<<<(CHUNKS * NCH / 8) / 256, 256, 0, stream>>>(Kb, Vb, td, sumN, sumD);
  wkv_pass2<<<192, 256, 0, stream>>>(sumN, sumD, td, prefN, prefD, gstats);
  wkv_pass3<<<(CHUNKS * NCH / 8) / 256, 256, 0, stream>>>(Kb, Vb, Rb, td, tf,
                                                          prefN, prefD, gstats, gstats + 96);

  // GN folded into output GEMM: Wo_b = Wo * (rstd*gw) per batch; bias2 = cB @ Wo^T
  wofuse_kernel<<<4704, 256, 0, stream>>>(Wo, gstats, gstats + 96, gw, gb, Wob, bias2);

  gemm_nt<0, 0, 1><<<ggrid, 256, 0, stream>>>(Rb, Wob, out, bias2);
}